// Round 1
// baseline (1490.819 us; speedup 1.0000x reference)
//
#include <hip/hip_runtime.h>

// EdgeConv block, fp32-exact-first implementation.
// Pipeline:
//  1. k_norms:      n2[i] = ||X_i||^2
//  2. k_pq:         P = X@(W1_top - W1_bot) + b1 ; Q = X@W1_bot      (layer-1 GEMM collapse)
//  3. k_dist_topk:  fused tiled distance + per-row top-16 (exact fp32, stable ties by index)
//  4. k_stats_edges: column sum/sumsq of pre1 = P[n]+Q[idx]          (block partials)
//  5. k_reduce_stats: mu/var -> a,c affine (BN fold)
//  6. k_gemm<2>:    A = relu(a1*(P[n]+Q[j])+c1) on the fly, *W2+b2 -> big, + stats partials
//  7. k_reduce_stats
//  8. k_gemm<3>:    A = relu(a2*big+c2), *W3+b3 -> big (in-place, rows block-exclusive), + stats
//  9. k_reduce_stats
// 10. k_final:      out[n] = sum_k relu(a3*big[n*16+k]+c3)

#define N_PTS 16384
#define FDIM  64
#define HDIM  128
#define KNN   16
#define NEDGE (N_PTS * KNN)

// ---------------------------------------------------------------- norms
__global__ __launch_bounds__(256)
void k_norms(const float* __restrict__ X, float* __restrict__ n2) {
  const int r = blockIdx.x * 256 + threadIdx.x;
  const float4* x4 = reinterpret_cast<const float4*>(X) + (size_t)r * (FDIM / 4);
  float p[16];
#pragma unroll
  for (int i = 0; i < 16; ++i) {
    const float4 v = x4[i];
    p[i] = (v.x * v.x + v.y * v.y) + (v.z * v.z + v.w * v.w);
  }
#pragma unroll
  for (int s = 1; s < 16; s <<= 1) {
#pragma unroll
    for (int i = 0; i < 16; i += 2 * s) p[i] += p[i + s];
  }
  n2[r] = p[0];
}

// ---------------------------------------------------------------- P,Q
__global__ __launch_bounds__(256)
void k_pq(const float* __restrict__ X, const float* __restrict__ W1,
          const float* __restrict__ b1, float* __restrict__ P, float* __restrict__ Q) {
  const int h4 = threadIdx.x & 31;          // float4 column group (128 cols / 4)
  const int rsub = threadIdx.x >> 5;        // 8 rows per block
  const int row = blockIdx.x * 8 + rsub;
  const float* x = X + (size_t)row * FDIM;
  const float4* W14 = reinterpret_cast<const float4*>(W1);
  float4 at = make_float4(0.f, 0.f, 0.f, 0.f);
  float4 ab = make_float4(0.f, 0.f, 0.f, 0.f);
#pragma unroll 8
  for (int f = 0; f < FDIM; ++f) {
    const float xv = x[f];                  // broadcast across the 32 lanes of this row
    const float4 wt = W14[(size_t)f * 32 + h4];
    const float4 wb = W14[(size_t)(FDIM + f) * 32 + h4];
    at.x = fmaf(xv, wt.x, at.x); at.y = fmaf(xv, wt.y, at.y);
    at.z = fmaf(xv, wt.z, at.z); at.w = fmaf(xv, wt.w, at.w);
    ab.x = fmaf(xv, wb.x, ab.x); ab.y = fmaf(xv, wb.y, ab.y);
    ab.z = fmaf(xv, wb.z, ab.z); ab.w = fmaf(xv, wb.w, ab.w);
  }
  const float4 bb = reinterpret_cast<const float4*>(b1)[h4];
  float4 pv;
  pv.x = at.x - ab.x + bb.x; pv.y = at.y - ab.y + bb.y;
  pv.z = at.z - ab.z + bb.z; pv.w = at.w - ab.w + bb.w;
  reinterpret_cast<float4*>(P)[(size_t)row * 32 + h4] = pv;
  reinterpret_cast<float4*>(Q)[(size_t)row * 32 + h4] = ab;
}

// ---------------------------------------------------------------- fused distance + top-16
// Block: 256 thr = 4 waves; 32 query rows/block; j-chunks of 128 (two 64-col halves).
// Wave w: rows (w&1)*16 .. +15, j-half (w>>1). Lane = 4x4 register tile.
// Per-lane private sorted top-16 (u64 keys: order-preserved fp32 | index). End: 8-list merge/row.
__global__ __launch_bounds__(256, 2)
void k_dist_topk(const float* __restrict__ X, const float* __restrict__ n2g,
                 int* __restrict__ knn) {
  __shared__ __align__(16) char smem[60928];
  float (*XiT)[36]  = reinterpret_cast<float(*)[36]>(smem);           // [64][36]   f-major Xi^T
  float (*XjT)[132] = reinterpret_cast<float(*)[132]>(smem + 9216);   // [64][132]  f-major Xj^T
  float* n2j        = reinterpret_cast<float*>(smem + 43008);         // [128]
  float (*sc)[16][68] = reinterpret_cast<float(*)[16][68]>(smem + 43520); // [4][16][68]

  const int tid = threadIdx.x;
  const int w = tid >> 6, lane = tid & 63;
  const int rg = lane >> 4, cg = lane & 15;
  const int i0 = blockIdx.x * 32;
  const int wrow0 = (w & 1) * 16;
  const int jhalf = (w >> 1) * 64;
  const int r_own = lane & 15;
  const int q_own = lane >> 4;

  const float4* X4 = reinterpret_cast<const float4*>(X);

  // stage Xi^T once
  for (int u = tid; u < 32 * 16; u += 256) {
    const int r = u >> 4, f4 = u & 15;
    const float4 v = X4[(size_t)(i0 + r) * 16 + f4];
    XiT[f4 * 4 + 0][r] = v.x; XiT[f4 * 4 + 1][r] = v.y;
    XiT[f4 * 4 + 2][r] = v.z; XiT[f4 * 4 + 3][r] = v.w;
  }
  float n2i[4];
#pragma unroll
  for (int a = 0; a < 4; ++a) n2i[a] = n2g[i0 + wrow0 + rg * 4 + a];

  unsigned long long list[16];
#pragma unroll
  for (int p = 0; p < 16; ++p) list[p] = 0xFFFFFFFFFFFFFFFFULL;

  for (int jb = 0; jb < N_PTS; jb += 128) {
    __syncthreads();
    for (int u = tid; u < 128 * 16; u += 256) {
      const int r = u >> 4, f4 = u & 15;
      const float4 v = X4[(size_t)(jb + r) * 16 + f4];
      XjT[f4 * 4 + 0][r] = v.x; XjT[f4 * 4 + 1][r] = v.y;
      XjT[f4 * 4 + 2][r] = v.z; XjT[f4 * 4 + 3][r] = v.w;
    }
    if (tid < 128) n2j[tid] = n2g[jb + tid];
    __syncthreads();

    float acc[4][4] = {};
#pragma unroll 16
    for (int f = 0; f < 64; ++f) {
      const float4 xi = *reinterpret_cast<const float4*>(&XiT[f][wrow0 + rg * 4]);
      const float4 xj = *reinterpret_cast<const float4*>(&XjT[f][jhalf + cg * 4]);
      acc[0][0] = fmaf(xi.x, xj.x, acc[0][0]); acc[0][1] = fmaf(xi.x, xj.y, acc[0][1]);
      acc[0][2] = fmaf(xi.x, xj.z, acc[0][2]); acc[0][3] = fmaf(xi.x, xj.w, acc[0][3]);
      acc[1][0] = fmaf(xi.y, xj.x, acc[1][0]); acc[1][1] = fmaf(xi.y, xj.y, acc[1][1]);
      acc[1][2] = fmaf(xi.y, xj.z, acc[1][2]); acc[1][3] = fmaf(xi.y, xj.w, acc[1][3]);
      acc[2][0] = fmaf(xi.z, xj.x, acc[2][0]); acc[2][1] = fmaf(xi.z, xj.y, acc[2][1]);
      acc[2][2] = fmaf(xi.z, xj.z, acc[2][2]); acc[2][3] = fmaf(xi.z, xj.w, acc[2][3]);
      acc[3][0] = fmaf(xi.w, xj.x, acc[3][0]); acc[3][1] = fmaf(xi.w, xj.y, acc[3][1]);
      acc[3][2] = fmaf(xi.w, xj.z, acc[3][2]); acc[3][3] = fmaf(xi.w, xj.w, acc[3][3]);
    }

    // scores, mimicking reference association: (n2i + n2j) - 2*dot, no contraction
#pragma unroll
    for (int a = 0; a < 4; ++a) {
      float s[4];
#pragma unroll
      for (int b = 0; b < 4; ++b) {
        const float t = n2i[a] + n2j[jhalf + cg * 4 + b];
        s[b] = __fsub_rn(t, __fmul_rn(2.0f, acc[a][b]));
      }
      *reinterpret_cast<float4*>(&sc[w][rg * 4 + a][cg * 4]) =
          make_float4(s[0], s[1], s[2], s[3]);
    }
    __syncthreads();   // conservative: order score writes vs cross-lane reads

    // filter 16 candidates belonging to this lane's (row, quarter)
    const int jcb = jhalf + q_own * 16;
#pragma unroll
    for (int u = 0; u < 4; ++u) {
      const float4 v = *reinterpret_cast<const float4*>(&sc[w][r_own][q_own * 16 + u * 4]);
      const float vv[4] = {v.x, v.y, v.z, v.w};
#pragma unroll
      for (int e2 = 0; e2 < 4; ++e2) {
        unsigned int ub = __float_as_uint(vv[e2]);
        ub = (ub & 0x80000000u) ? ~ub : (ub | 0x80000000u);
        const unsigned long long key =
            ((unsigned long long)ub << 32) | (unsigned int)(jb + jcb + u * 4 + e2);
        if (key < list[15]) {
#pragma unroll
          for (int p = 15; p >= 1; --p) {
            const unsigned long long prev = list[p - 1];
            unsigned long long cur = list[p];
            cur = (key < cur) ? key : cur;
            list[p] = (key < prev) ? prev : cur;
          }
          list[0] = (key < list[0]) ? key : list[0];
        }
      }
    }
  }

  // merge: 8 sorted 16-lists per row -> top 16
  __syncthreads();
  unsigned long long* mb = reinterpret_cast<unsigned long long*>(smem); // 32KB alias over XiT/XjT
  {
    const int row_l = wrow0 + r_own;
    const int qg = (w >> 1) * 4 + q_own;
#pragma unroll
    for (int p = 0; p < 16; ++p) mb[((size_t)row_l * 8 + qg) * 16 + p] = list[p];
  }
  __syncthreads();
  if (tid < 32) {
    int pp[8] = {0, 0, 0, 0, 0, 0, 0, 0};
    for (int pick = 0; pick < KNN; ++pick) {
      unsigned long long best = 0xFFFFFFFFFFFFFFFFULL; int bq = 0;
#pragma unroll
      for (int q = 0; q < 8; ++q) {
        const unsigned long long cand =
            (pp[q] < 16) ? mb[((size_t)tid * 8 + q) * 16 + pp[q]] : 0xFFFFFFFFFFFFFFFFULL;
        if (cand < best) { best = cand; bq = q; }
      }
      pp[bq]++;
      knn[(size_t)(i0 + tid) * KNN + pick] = (int)(unsigned int)(best & 0xFFFFFFFFULL);
    }
  }
}

// ---------------------------------------------------------------- stats of pre1
__global__ __launch_bounds__(256)
void k_stats_edges(const float* __restrict__ P, const float* __restrict__ Q,
                   const int* __restrict__ idx,
                   double* __restrict__ psum, double* __restrict__ psq) {
  __shared__ double sd[2][128];
  __shared__ double qd[2][128];
  const int t = threadIdx.x;
  const int h = t & 127, half = t >> 7;
  const size_t e0 = (size_t)blockIdx.x * 128;
  double s = 0.0, q = 0.0;
  for (int it = 0; it < 64; ++it) {
    const size_t e = e0 + (size_t)it * 2 + half;
    const int n = (int)(e >> 4);
    const int j = idx[e];
    const float v = P[(size_t)n * HDIM + h] + Q[(size_t)j * HDIM + h];
    s += (double)v;
    q += (double)v * (double)v;
  }
  sd[half][h] = s; qd[half][h] = q;
  __syncthreads();
  if (t < 128) {
    psum[(size_t)blockIdx.x * 128 + t] = sd[0][t] + sd[1][t];
    psq[(size_t)blockIdx.x * 128 + t]  = qd[0][t] + qd[1][t];
  }
}

// ---------------------------------------------------------------- stats reduce -> a,c
__global__ __launch_bounds__(256)
void k_reduce_stats(const double* __restrict__ psum, const double* __restrict__ psq,
                    const float* __restrict__ g, const float* __restrict__ beta,
                    float* __restrict__ aout, float* __restrict__ cout) {
  __shared__ double sbuf[256];
  __shared__ double qbuf[256];
  const int h = blockIdx.x, t = threadIdx.x;
  double s = 0.0, q = 0.0;
  for (int i = t; i < 2048; i += 256) {
    s += psum[(size_t)i * 128 + h];
    q += psq[(size_t)i * 128 + h];
  }
  sbuf[t] = s; qbuf[t] = q;
  __syncthreads();
  for (int st = 128; st > 0; st >>= 1) {
    if (t < st) { sbuf[t] += sbuf[t + st]; qbuf[t] += qbuf[t + st]; }
    __syncthreads();
  }
  if (t == 0) {
    const double cnt = (double)NEDGE;
    const double mu = sbuf[0] / cnt;
    double var = qbuf[0] / cnt - mu * mu;
    if (var < 0.0) var = 0.0;
    const double rs = 1.0 / sqrt(var + 1e-5);
    const double a = (double)g[h] * rs;
    aout[h] = (float)a;
    cout[h] = (float)((double)beta[h] - mu * a);
  }
}

// ---------------------------------------------------------------- GEMM (layers 2 & 3)
// 128 edges x 128 cols per block, K=128 in 4 steps of 32. Stats partials in epilogue.
template <int MODE>
__global__ __launch_bounds__(256, 2)
void k_gemm(const float* __restrict__ P, const float* __restrict__ Q,
            const int* __restrict__ idx, float* __restrict__ big,
            const float* __restrict__ Wg, const float* __restrict__ bias,
            const float* __restrict__ aff_a, const float* __restrict__ aff_c,
            double* __restrict__ psum, double* __restrict__ psq) {
  __shared__ float A_lds[32][132];
  __shared__ float B_lds[32][132];
  const int tid = threadIdx.x;
  const int tm = tid & 15, tn = tid >> 4;
  const size_t e0 = (size_t)blockIdx.x * 128;

  float acc[2][2][4][4] = {};

  for (int kk = 0; kk < 128; kk += 32) {
    __syncthreads();
    {  // stage A (fused BN+ReLU producer)
      const int k4 = tid & 7;
      const int mrow = tid >> 3;
      const float4 av = reinterpret_cast<const float4*>(aff_a)[(kk >> 2) + k4];
      const float4 cv = reinterpret_cast<const float4*>(aff_c)[(kk >> 2) + k4];
#pragma unroll
      for (int p = 0; p < 4; ++p) {
        const int m = p * 32 + mrow;
        const size_t e = e0 + m;
        float4 hv;
        if (MODE == 2) {
          const int n = (int)(e >> 4);
          const int j = idx[e];
          const float4 pv = reinterpret_cast<const float4*>(P)[(size_t)n * 32 + (kk >> 2) + k4];
          const float4 qv = reinterpret_cast<const float4*>(Q)[(size_t)j * 32 + (kk >> 2) + k4];
          hv.x = pv.x + qv.x; hv.y = pv.y + qv.y; hv.z = pv.z + qv.z; hv.w = pv.w + qv.w;
        } else {
          hv = reinterpret_cast<const float4*>(big)[e * 32 + (kk >> 2) + k4];
        }
        A_lds[k4 * 4 + 0][m] = fmaxf(fmaf(av.x, hv.x, cv.x), 0.0f);
        A_lds[k4 * 4 + 1][m] = fmaxf(fmaf(av.y, hv.y, cv.y), 0.0f);
        A_lds[k4 * 4 + 2][m] = fmaxf(fmaf(av.z, hv.z, cv.z), 0.0f);
        A_lds[k4 * 4 + 3][m] = fmaxf(fmaf(av.w, hv.w, cv.w), 0.0f);
      }
    }
    {  // stage B
      const int f4c = tid & 31;
      const int rb = tid >> 5;
#pragma unroll
      for (int p = 0; p < 4; ++p) {
        const int r = p * 8 + rb;
        const float4 wv = reinterpret_cast<const float4*>(Wg)[(size_t)(kk + r) * 32 + f4c];
        *reinterpret_cast<float4*>(&B_lds[r][f4c * 4]) = wv;
      }
    }
    __syncthreads();
#pragma unroll 4
    for (int k = 0; k < 32; ++k) {
      const float4 a0 = *reinterpret_cast<const float4*>(&A_lds[k][tm * 4]);
      const float4 a1 = *reinterpret_cast<const float4*>(&A_lds[k][64 + tm * 4]);
      const float4 b0 = *reinterpret_cast<const float4*>(&B_lds[k][tn * 4]);
      const float4 b1 = *reinterpret_cast<const float4*>(&B_lds[k][64 + tn * 4]);
      const float avv[2][4] = {{a0.x, a0.y, a0.z, a0.w}, {a1.x, a1.y, a1.z, a1.w}};
      const float bvv[2][4] = {{b0.x, b0.y, b0.z, b0.w}, {b1.x, b1.y, b1.z, b1.w}};
#pragma unroll
      for (int rh = 0; rh < 2; ++rh)
#pragma unroll
        for (int a = 0; a < 4; ++a)
#pragma unroll
          for (int ch = 0; ch < 2; ++ch)
#pragma unroll
            for (int b = 0; b < 4; ++b)
              acc[rh][ch][a][b] = fmaf(avv[rh][a], bvv[ch][b], acc[rh][ch][a][b]);
    }
  }

  __syncthreads();
  float sumf[2][4] = {{0, 0, 0, 0}, {0, 0, 0, 0}};
  float sqf[2][4]  = {{0, 0, 0, 0}, {0, 0, 0, 0}};
  const float4 bbl = reinterpret_cast<const float4*>(bias)[tn];
  const float4 bbh = reinterpret_cast<const float4*>(bias)[16 + tn];
  const float bb[2][4] = {{bbl.x, bbl.y, bbl.z, bbl.w}, {bbh.x, bbh.y, bbh.z, bbh.w}};
#pragma unroll
  for (int rh = 0; rh < 2; ++rh) {
#pragma unroll
    for (int a = 0; a < 4; ++a) {
      const size_t e = e0 + rh * 64 + tm * 4 + a;
#pragma unroll
      for (int ch = 0; ch < 2; ++ch) {
        float v[4];
#pragma unroll
        for (int b = 0; b < 4; ++b) {
          v[b] = acc[rh][ch][a][b] + bb[ch][b];
          sumf[ch][b] += v[b];
          sqf[ch][b] = fmaf(v[b], v[b], sqf[ch][b]);
        }
        float4 vv; vv.x = v[0]; vv.y = v[1]; vv.z = v[2]; vv.w = v[3];
        reinterpret_cast<float4*>(big)[e * 32 + ch * 16 + tn] = vv;
      }
    }
  }
  float* sds = reinterpret_cast<float*>(&A_lds[0][0]);  // 16x128 floats
  float* sdq = reinterpret_cast<float*>(&B_lds[0][0]);
#pragma unroll
  for (int ch = 0; ch < 2; ++ch)
#pragma unroll
    for (int b = 0; b < 4; ++b) {
      sds[tm * 128 + ch * 64 + tn * 4 + b] = sumf[ch][b];
      sdq[tm * 128 + ch * 64 + tn * 4 + b] = sqf[ch][b];
    }
  __syncthreads();
  if (tid < 128) {
    double s = 0.0, q = 0.0;
#pragma unroll
    for (int m2 = 0; m2 < 16; ++m2) {
      s += (double)sds[m2 * 128 + tid];
      q += (double)sdq[m2 * 128 + tid];
    }
    psum[(size_t)blockIdx.x * 128 + tid] = s;
    psq[(size_t)blockIdx.x * 128 + tid]  = q;
  }
}

// ---------------------------------------------------------------- final BN+ReLU+sum over K
__global__ __launch_bounds__(256)
void k_final(const float* __restrict__ big, const float* __restrict__ a3,
             const float* __restrict__ c3, float* __restrict__ out) {
  const int t = threadIdx.x;
  const int h = t & 127, ns = t >> 7;
  const size_t n = (size_t)blockIdx.x * 2 + ns;
  const float aa = a3[h], cc = c3[h];
  float s = 0.0f;
#pragma unroll
  for (int k = 0; k < KNN; ++k) {
    const float x = big[(n * KNN + k) * HDIM + h];
    s += fmaxf(fmaf(aa, x, cc), 0.0f);
  }
  out[n * HDIM + h] = s;
}

// ---------------------------------------------------------------- launch
extern "C" void kernel_launch(void* const* d_in, const int* in_sizes, int n_in,
                              void* d_out, int out_size, void* d_ws, size_t ws_size,
                              hipStream_t stream) {
  (void)in_sizes; (void)n_in; (void)out_size;
  const float* X   = (const float*)d_in[0];
  const float* W1  = (const float*)d_in[1];
  const float* b1  = (const float*)d_in[2];
  const float* g1  = (const float*)d_in[3];
  const float* be1 = (const float*)d_in[4];
  const float* W2  = (const float*)d_in[5];
  const float* b2  = (const float*)d_in[6];
  const float* g2  = (const float*)d_in[7];
  const float* be2 = (const float*)d_in[8];
  const float* W3  = (const float*)d_in[9];
  const float* b3  = (const float*)d_in[10];
  const float* g3  = (const float*)d_in[11];
  const float* be3 = (const float*)d_in[12];
  float* out = (float*)d_out;

  char* w = (char*)d_ws;
  size_t off = 0;
  auto carve = [&](size_t bytes) -> char* {
    char* p = w + off;
    off = (off + bytes + 255) & ~(size_t)255;
    return p;
  };
  float*  n2   = (float*)carve((size_t)N_PTS * 4);
  float*  P    = (float*)carve((size_t)N_PTS * HDIM * 4);
  float*  Q    = (float*)carve((size_t)N_PTS * HDIM * 4);
  int*    knn  = (int*)carve((size_t)NEDGE * 4);
  double* ps1  = (double*)carve((size_t)2048 * 128 * 8);
  double* pq1  = (double*)carve((size_t)2048 * 128 * 8);
  double* ps2  = (double*)carve((size_t)2048 * 128 * 8);
  double* pq2  = (double*)carve((size_t)2048 * 128 * 8);
  double* ps3  = (double*)carve((size_t)2048 * 128 * 8);
  double* pq3  = (double*)carve((size_t)2048 * 128 * 8);
  float*  a1   = (float*)carve(512);
  float*  c1   = (float*)carve(512);
  float*  a2   = (float*)carve(512);
  float*  c2   = (float*)carve(512);
  float*  a3   = (float*)carve(512);
  float*  c3   = (float*)carve(512);
  float*  big  = (float*)carve((size_t)NEDGE * HDIM * 4);
  if (off > ws_size) return;  // ws too small: leave d_out poisoned as a clear signal

  k_norms<<<dim3(N_PTS / 256), dim3(256), 0, stream>>>(X, n2);
  k_pq<<<dim3(N_PTS / 8), dim3(256), 0, stream>>>(X, W1, b1, P, Q);
  k_dist_topk<<<dim3(N_PTS / 32), dim3(256), 0, stream>>>(X, n2, knn);
  k_stats_edges<<<dim3(2048), dim3(256), 0, stream>>>(P, Q, knn, ps1, pq1);
  k_reduce_stats<<<dim3(128), dim3(256), 0, stream>>>(ps1, pq1, g1, be1, a1, c1);
  k_gemm<2><<<dim3(NEDGE / 128), dim3(256), 0, stream>>>(P, Q, knn, big, W2, b2, a1, c1, ps2, pq2);
  k_reduce_stats<<<dim3(128), dim3(256), 0, stream>>>(ps2, pq2, g2, be2, a2, c2);
  k_gemm<3><<<dim3(NEDGE / 128), dim3(256), 0, stream>>>(P, Q, knn, big, W3, b3, a2, c2, ps3, pq3);
  k_reduce_stats<<<dim3(128), dim3(256), 0, stream>>>(ps3, pq3, g3, be3, a3, c3);
  k_final<<<dim3(N_PTS / 2), dim3(256), 0, stream>>>(big, a3, c3, out);
}

// Round 2
// 1226.379 us; speedup vs baseline: 1.2156x; 1.2156x over previous
//
#include <hip/hip_runtime.h>

// EdgeConv block. Round 2: dist/topk kernel overhauled
//  - defer-and-batch top-16 (shared per-row threshold + per-lane LDS ring +
//    ballot-gated compaction) replaces the per-candidate wave-divergent ladder
//  - XOR-swizzled LDS staging (kills 8-way bank conflicts on transpose writes)
//  - 2 barriers per j-chunk instead of 3 (sc/ring/thr are wave-private)
// Rest of pipeline (P/Q trick, fused-BN GEMMs, stats, final) unchanged.

#define N_PTS 16384
#define FDIM  64
#define HDIM  128
#define KNN   16
#define NEDGE (N_PTS * KNN)

#define SENT_KEY 0xFF800000FFFFFFFFull  // packed(+inf) | idx:all-ones
#define MAXU64   0xFFFFFFFFFFFFFFFFull

// ---------------------------------------------------------------- norms
__global__ __launch_bounds__(256)
void k_norms(const float* __restrict__ X, float* __restrict__ n2) {
  const int r = blockIdx.x * 256 + threadIdx.x;
  const float4* x4 = reinterpret_cast<const float4*>(X) + (size_t)r * (FDIM / 4);
  float p[16];
#pragma unroll
  for (int i = 0; i < 16; ++i) {
    const float4 v = x4[i];
    p[i] = (v.x * v.x + v.y * v.y) + (v.z * v.z + v.w * v.w);
  }
#pragma unroll
  for (int s = 1; s < 16; s <<= 1) {
#pragma unroll
    for (int i = 0; i < 16; i += 2 * s) p[i] += p[i + s];
  }
  n2[r] = p[0];
}

// ---------------------------------------------------------------- P,Q
__global__ __launch_bounds__(256)
void k_pq(const float* __restrict__ X, const float* __restrict__ W1,
          const float* __restrict__ b1, float* __restrict__ P, float* __restrict__ Q) {
  const int h4 = threadIdx.x & 31;
  const int rsub = threadIdx.x >> 5;
  const int row = blockIdx.x * 8 + rsub;
  const float* x = X + (size_t)row * FDIM;
  const float4* W14 = reinterpret_cast<const float4*>(W1);
  float4 at = make_float4(0.f, 0.f, 0.f, 0.f);
  float4 ab = make_float4(0.f, 0.f, 0.f, 0.f);
#pragma unroll 8
  for (int f = 0; f < FDIM; ++f) {
    const float xv = x[f];
    const float4 wt = W14[(size_t)f * 32 + h4];
    const float4 wb = W14[(size_t)(FDIM + f) * 32 + h4];
    at.x = fmaf(xv, wt.x, at.x); at.y = fmaf(xv, wt.y, at.y);
    at.z = fmaf(xv, wt.z, at.z); at.w = fmaf(xv, wt.w, at.w);
    ab.x = fmaf(xv, wb.x, ab.x); ab.y = fmaf(xv, wb.y, ab.y);
    ab.z = fmaf(xv, wb.z, ab.z); ab.w = fmaf(xv, wb.w, ab.w);
  }
  const float4 bb = reinterpret_cast<const float4*>(b1)[h4];
  float4 pv;
  pv.x = at.x - ab.x + bb.x; pv.y = at.y - ab.y + bb.y;
  pv.z = at.z - ab.z + bb.z; pv.w = at.w - ab.w + bb.w;
  reinterpret_cast<float4*>(P)[(size_t)row * 32 + h4] = pv;
  reinterpret_cast<float4*>(Q)[(size_t)row * 32 + h4] = ab;
}

// ---------------------------------------------------------------- fused distance + top-16
// Block: 256 thr = 4 waves; 32 query rows/block; j-chunks of 128.
// Wave w: rows (w&1)*16..+15, j-half (w>>1)*64..+63, lane tile 4x4.
// Filter: shared per-row threshold (min over 8 owner lanes' 16th-best) gates
// appends into a per-lane 6-slot LDS ring; ballot-gated compaction ladders
// ring entries into the per-lane sorted 16-list (u64 key = ord-score||j).
//
// LDS map (bytes):               swizzles (word-index XOR):
//  0     XiT  [64][32]  8192     col ^ 4*((f>>2)&7)
//  8192  XjT  [64][128] 32768    col ^ 4*((f>>2)&7)
//  40960 sc   [4][16][36] 9216   col ^ 4*(row&7)
//  50176 n2j  [128]      512
//  50688 thr  [32][8]    1024
//  51712 ring [6][256]  12288
//  total 64000;  mb(final) aliases bytes 0..32767
__global__ __launch_bounds__(256, 2)
void k_dist_topk(const float* __restrict__ X, const float* __restrict__ n2g,
                 int* __restrict__ knn) {
  __shared__ __align__(16) char smem[64000];
  float* XiT = reinterpret_cast<float*>(smem);                 // [64*32]
  float* XjT = reinterpret_cast<float*>(smem + 8192);          // [64*128]
  float* scb = reinterpret_cast<float*>(smem + 40960);         // [4][16*36]
  float* n2j = reinterpret_cast<float*>(smem + 50176);         // [128]
  float* thr = reinterpret_cast<float*>(smem + 50688);         // [32][8]
  unsigned long long* ring = reinterpret_cast<unsigned long long*>(smem + 51712); // [6][256]

  const int tid = threadIdx.x;
  const int w = tid >> 6, lane = tid & 63;
  const int rg = lane >> 4, cg = lane & 15;
  const int i0 = blockIdx.x * 32;
  const int wrow0 = (w & 1) * 16;
  const int jhalf = (w >> 1) * 64;
  const int r_own = lane & 15;
  const int q_own = lane >> 4;
  const int row_l = wrow0 + r_own;             // 0..31
  const int lslot = (w >> 1) * 4 + q_own;      // 0..7
  float* scw = scb + w * (16 * 36);

  const float4* X4 = reinterpret_cast<const float4*>(X);

  // init shared thresholds to +inf (one slot per thread), then stage Xi^T
  thr[tid] = __int_as_float(0x7f800000);
  for (int u = tid; u < 32 * 16; u += 256) {
    const int r = u >> 4, f4 = u & 15;
    const float4 v = X4[(size_t)(i0 + r) * 16 + f4];
    const int cs = r ^ (4 * (f4 & 7));  // (f>>2)&7 == f4&7 for f=f4*4+c
    XiT[(f4 * 4 + 0) * 32 + cs] = v.x;
    XiT[(f4 * 4 + 1) * 32 + cs] = v.y;
    XiT[(f4 * 4 + 2) * 32 + cs] = v.z;
    XiT[(f4 * 4 + 3) * 32 + cs] = v.w;
  }
  float n2i[4];
#pragma unroll
  for (int a = 0; a < 4; ++a) n2i[a] = n2g[i0 + wrow0 + rg * 4 + a];

  unsigned long long list[16];
#pragma unroll
  for (int p = 0; p < 16; ++p) list[p] = SENT_KEY;
  int cnt = 0;

  const int ixc = wrow0 + rg * 4;
  const int jxc = jhalf + cg * 4;

  for (int jb = 0; jb < N_PTS; jb += 128) {
    __syncthreads();   // protect XjT/n2j overwrite vs all-wave reads of prev chunk
    for (int u = tid; u < 128 * 16; u += 256) {
      const int r = u >> 4, f4 = u & 15;
      const float4 v = X4[(size_t)(jb + r) * 16 + f4];
      const int cs = r ^ (4 * (f4 & 7));
      XjT[(f4 * 4 + 0) * 128 + cs] = v.x;
      XjT[(f4 * 4 + 1) * 128 + cs] = v.y;
      XjT[(f4 * 4 + 2) * 128 + cs] = v.z;
      XjT[(f4 * 4 + 3) * 128 + cs] = v.w;
    }
    if (tid < 128) n2j[tid] = n2g[jb + tid];
    __syncthreads();

    // ---- 64-deep dot-product accumulation, 4x4 per lane
    float acc[4][4] = {};
#pragma unroll
    for (int fo = 0; fo < 16; ++fo) {
      const int ksz = 4 * (fo & 7);
      const int ia = ixc ^ ksz;
      const int ja = jxc ^ ksz;
#pragma unroll
      for (int c = 0; c < 4; ++c) {
        const int f = fo * 4 + c;
        const float4 xi = *reinterpret_cast<const float4*>(&XiT[f * 32 + ia]);
        const float4 xj = *reinterpret_cast<const float4*>(&XjT[f * 128 + ja]);
        acc[0][0] = fmaf(xi.x, xj.x, acc[0][0]); acc[0][1] = fmaf(xi.x, xj.y, acc[0][1]);
        acc[0][2] = fmaf(xi.x, xj.z, acc[0][2]); acc[0][3] = fmaf(xi.x, xj.w, acc[0][3]);
        acc[1][0] = fmaf(xi.y, xj.x, acc[1][0]); acc[1][1] = fmaf(xi.y, xj.y, acc[1][1]);
        acc[1][2] = fmaf(xi.y, xj.z, acc[1][2]); acc[1][3] = fmaf(xi.y, xj.w, acc[1][3]);
        acc[2][0] = fmaf(xi.z, xj.x, acc[2][0]); acc[2][1] = fmaf(xi.z, xj.y, acc[2][1]);
        acc[2][2] = fmaf(xi.z, xj.z, acc[2][2]); acc[2][3] = fmaf(xi.z, xj.w, acc[2][3]);
        acc[3][0] = fmaf(xi.w, xj.x, acc[3][0]); acc[3][1] = fmaf(xi.w, xj.y, acc[3][1]);
        acc[3][2] = fmaf(xi.w, xj.z, acc[3][2]); acc[3][3] = fmaf(xi.w, xj.w, acc[3][3]);
      }
    }

    const float4 n2v = *reinterpret_cast<const float4*>(&n2j[jhalf + cg * 4]);
    const float n2a[4] = {n2v.x, n2v.y, n2v.z, n2v.w};

    // ---- two 32-col passes: score scatter (half lanes) + filter (all lanes)
#pragma unroll
    for (int p = 0; p < 2; ++p) {
      if ((cg >> 3) == p) {
        const int c8 = cg & 7;
#pragma unroll
        for (int a = 0; a < 4; ++a) {
          const int row = rg * 4 + a;
          float s[4];
#pragma unroll
          for (int b = 0; b < 4; ++b) {
            const float t = n2i[a] + n2a[b];
            s[b] = __fsub_rn(t, __fmul_rn(2.0f, acc[a][b]));
          }
          const int cw = (c8 * 4) ^ (4 * (row & 7));
          *reinterpret_cast<float4*>(&scw[row * 36 + cw]) =
              make_float4(s[0], s[1], s[2], s[3]);
        }
      }
      // same-wave DS FIFO ordering makes these writes visible to the reads below

      const float4 t0 = *reinterpret_cast<const float4*>(&thr[row_l * 8]);
      const float4 t1 = *reinterpret_cast<const float4*>(&thr[row_l * 8 + 4]);
      const float thrm = fminf(fminf(fminf(t0.x, t0.y), fminf(t0.z, t0.w)),
                               fminf(fminf(t1.x, t1.y), fminf(t1.z, t1.w)));
      const int jg0 = jb + jhalf + p * 32 + q_own * 8;

#pragma unroll
      for (int u = 0; u < 2; ++u) {
        const int cw = (q_own * 8 + u * 4) ^ (4 * (r_own & 7));
        const float4 v = *reinterpret_cast<const float4*>(&scw[r_own * 36 + cw]);
        const float vv[4] = {v.x, v.y, v.z, v.w};
#pragma unroll
        for (int e2 = 0; e2 < 4; ++e2) {
          if (vv[e2] <= thrm) {
            unsigned int ub = __float_as_uint(vv[e2]);
            ub = (ub & 0x80000000u) ? ~ub : (ub | 0x80000000u);
            ring[cnt * 256 + tid] =
                ((unsigned long long)ub << 32) | (unsigned int)(jg0 + u * 4 + e2);
            ++cnt;
          }
        }
        if (__any(cnt >= 3)) {
          // ---- compaction: ladder ring entries into sorted list
#pragma unroll
          for (int s = 0; s < 6; ++s) {
            const unsigned long long key =
                (s < cnt) ? ring[s * 256 + tid] : MAXU64;
            if (key < list[15]) {
#pragma unroll
              for (int q = 15; q >= 1; --q) {
                const unsigned long long prev = list[q - 1];
                unsigned long long cur = list[q];
                cur = (key < cur) ? key : cur;
                list[q] = (key < prev) ? prev : cur;
              }
              list[0] = (key < list[0]) ? key : list[0];
            }
          }
          cnt = 0;
          const unsigned int ub = (unsigned int)(list[15] >> 32);
          const float tf = (ub & 0x80000000u) ? __uint_as_float(ub & 0x7fffffffu)
                                              : __uint_as_float(~ub);
          thr[row_l * 8 + lslot] = tf;
        }
      }
    }
  }

  // final flush
  if (__any(cnt > 0)) {
#pragma unroll
    for (int s = 0; s < 6; ++s) {
      const unsigned long long key = (s < cnt) ? ring[s * 256 + tid] : MAXU64;
      if (key < list[15]) {
#pragma unroll
        for (int q = 15; q >= 1; --q) {
          const unsigned long long prev = list[q - 1];
          unsigned long long cur = list[q];
          cur = (key < cur) ? key : cur;
          list[q] = (key < prev) ? prev : cur;
        }
        list[0] = (key < list[0]) ? key : list[0];
      }
    }
  }

  // merge: 8 sorted 16-lists per row -> top 16
  __syncthreads();
  unsigned long long* mb = reinterpret_cast<unsigned long long*>(smem); // 32KB alias
  {
#pragma unroll
    for (int p = 0; p < 16; ++p) mb[((size_t)row_l * 8 + lslot) * 16 + p] = list[p];
  }
  __syncthreads();
  if (tid < 32) {
    int pp[8] = {0, 0, 0, 0, 0, 0, 0, 0};
    for (int pick = 0; pick < KNN; ++pick) {
      unsigned long long best = MAXU64; int bq = 0;
#pragma unroll
      for (int q = 0; q < 8; ++q) {
        const unsigned long long cand =
            (pp[q] < 16) ? mb[((size_t)tid * 8 + q) * 16 + pp[q]] : MAXU64;
        if (cand < best) { best = cand; bq = q; }
      }
      pp[bq]++;
      knn[(size_t)(i0 + tid) * KNN + pick] = (int)(unsigned int)(best & 0xFFFFFFFFULL);
    }
  }
}

// ---------------------------------------------------------------- stats of pre1
__global__ __launch_bounds__(256)
void k_stats_edges(const float* __restrict__ P, const float* __restrict__ Q,
                   const int* __restrict__ idx,
                   double* __restrict__ psum, double* __restrict__ psq) {
  __shared__ double sd[2][128];
  __shared__ double qd[2][128];
  const int t = threadIdx.x;
  const int h = t & 127, half = t >> 7;
  const size_t e0 = (size_t)blockIdx.x * 128;
  double s = 0.0, q = 0.0;
  for (int it = 0; it < 64; ++it) {
    const size_t e = e0 + (size_t)it * 2 + half;
    const int n = (int)(e >> 4);
    const int j = idx[e];
    const float v = P[(size_t)n * HDIM + h] + Q[(size_t)j * HDIM + h];
    s += (double)v;
    q += (double)v * (double)v;
  }
  sd[half][h] = s; qd[half][h] = q;
  __syncthreads();
  if (t < 128) {
    psum[(size_t)blockIdx.x * 128 + t] = sd[0][t] + sd[1][t];
    psq[(size_t)blockIdx.x * 128 + t]  = qd[0][t] + qd[1][t];
  }
}

// ---------------------------------------------------------------- stats reduce -> a,c
__global__ __launch_bounds__(256)
void k_reduce_stats(const double* __restrict__ psum, const double* __restrict__ psq,
                    const float* __restrict__ g, const float* __restrict__ beta,
                    float* __restrict__ aout, float* __restrict__ cout) {
  __shared__ double sbuf[256];
  __shared__ double qbuf[256];
  const int h = blockIdx.x, t = threadIdx.x;
  double s = 0.0, q = 0.0;
  for (int i = t; i < 2048; i += 256) {
    s += psum[(size_t)i * 128 + h];
    q += psq[(size_t)i * 128 + h];
  }
  sbuf[t] = s; qbuf[t] = q;
  __syncthreads();
  for (int st = 128; st > 0; st >>= 1) {
    if (t < st) { sbuf[t] += sbuf[t + st]; qbuf[t] += qbuf[t + st]; }
    __syncthreads();
  }
  if (t == 0) {
    const double cnt = (double)NEDGE;
    const double mu = sbuf[0] / cnt;
    double var = qbuf[0] / cnt - mu * mu;
    if (var < 0.0) var = 0.0;
    const double rs = 1.0 / sqrt(var + 1e-5);
    const double a = (double)g[h] * rs;
    aout[h] = (float)a;
    cout[h] = (float)((double)beta[h] - mu * a);
  }
}

// ---------------------------------------------------------------- GEMM (layers 2 & 3)
template <int MODE>
__global__ __launch_bounds__(256, 2)
void k_gemm(const float* __restrict__ P, const float* __restrict__ Q,
            const int* __restrict__ idx, float* __restrict__ big,
            const float* __restrict__ Wg, const float* __restrict__ bias,
            const float* __restrict__ aff_a, const float* __restrict__ aff_c,
            double* __restrict__ psum, double* __restrict__ psq) {
  __shared__ float A_lds[32][132];
  __shared__ float B_lds[32][132];
  const int tid = threadIdx.x;
  const int tm = tid & 15, tn = tid >> 4;
  const size_t e0 = (size_t)blockIdx.x * 128;

  float acc[2][2][4][4] = {};

  for (int kk = 0; kk < 128; kk += 32) {
    __syncthreads();
    {
      const int k4 = tid & 7;
      const int mrow = tid >> 3;
      const float4 av = reinterpret_cast<const float4*>(aff_a)[(kk >> 2) + k4];
      const float4 cv = reinterpret_cast<const float4*>(aff_c)[(kk >> 2) + k4];
#pragma unroll
      for (int p = 0; p < 4; ++p) {
        const int m = p * 32 + mrow;
        const size_t e = e0 + m;
        float4 hv;
        if (MODE == 2) {
          const int n = (int)(e >> 4);
          const int j = idx[e];
          const float4 pv = reinterpret_cast<const float4*>(P)[(size_t)n * 32 + (kk >> 2) + k4];
          const float4 qv = reinterpret_cast<const float4*>(Q)[(size_t)j * 32 + (kk >> 2) + k4];
          hv.x = pv.x + qv.x; hv.y = pv.y + qv.y; hv.z = pv.z + qv.z; hv.w = pv.w + qv.w;
        } else {
          hv = reinterpret_cast<const float4*>(big)[e * 32 + (kk >> 2) + k4];
        }
        A_lds[k4 * 4 + 0][m] = fmaxf(fmaf(av.x, hv.x, cv.x), 0.0f);
        A_lds[k4 * 4 + 1][m] = fmaxf(fmaf(av.y, hv.y, cv.y), 0.0f);
        A_lds[k4 * 4 + 2][m] = fmaxf(fmaf(av.z, hv.z, cv.z), 0.0f);
        A_lds[k4 * 4 + 3][m] = fmaxf(fmaf(av.w, hv.w, cv.w), 0.0f);
      }
    }
    {
      const int f4c = tid & 31;
      const int rb = tid >> 5;
#pragma unroll
      for (int p = 0; p < 4; ++p) {
        const int r = p * 8 + rb;
        const float4 wv = reinterpret_cast<const float4*>(Wg)[(size_t)(kk + r) * 32 + f4c];
        *reinterpret_cast<float4*>(&B_lds[r][f4c * 4]) = wv;
      }
    }
    __syncthreads();
#pragma unroll 4
    for (int k = 0; k < 32; ++k) {
      const float4 a0 = *reinterpret_cast<const float4*>(&A_lds[k][tm * 4]);
      const float4 a1 = *reinterpret_cast<const float4*>(&A_lds[k][64 + tm * 4]);
      const float4 b0 = *reinterpret_cast<const float4*>(&B_lds[k][tn * 4]);
      const float4 b1 = *reinterpret_cast<const float4*>(&B_lds[k][64 + tn * 4]);
      const float avv[2][4] = {{a0.x, a0.y, a0.z, a0.w}, {a1.x, a1.y, a1.z, a1.w}};
      const float bvv[2][4] = {{b0.x, b0.y, b0.z, b0.w}, {b1.x, b1.y, b1.z, b1.w}};
#pragma unroll
      for (int rh = 0; rh < 2; ++rh)
#pragma unroll
        for (int a = 0; a < 4; ++a)
#pragma unroll
          for (int ch = 0; ch < 2; ++ch)
#pragma unroll
            for (int b = 0; b < 4; ++b)
              acc[rh][ch][a][b] = fmaf(avv[rh][a], bvv[ch][b], acc[rh][ch][a][b]);
    }
  }

  __syncthreads();
  float sumf[2][4] = {{0, 0, 0, 0}, {0, 0, 0, 0}};
  float sqf[2][4]  = {{0, 0, 0, 0}, {0, 0, 0, 0}};
  const float4 bbl = reinterpret_cast<const float4*>(bias)[tn];
  const float4 bbh = reinterpret_cast<const float4*>(bias)[16 + tn];
  const float bb[2][4] = {{bbl.x, bbl.y, bbl.z, bbl.w}, {bbh.x, bbh.y, bbh.z, bbh.w}};
#pragma unroll
  for (int rh = 0; rh < 2; ++rh) {
#pragma unroll
    for (int a = 0; a < 4; ++a) {
      const size_t e = e0 + rh * 64 + tm * 4 + a;
#pragma unroll
      for (int ch = 0; ch < 2; ++ch) {
        float v[4];
#pragma unroll
        for (int b = 0; b < 4; ++b) {
          v[b] = acc[rh][ch][a][b] + bb[ch][b];
          sumf[ch][b] += v[b];
          sqf[ch][b] = fmaf(v[b], v[b], sqf[ch][b]);
        }
        float4 vv; vv.x = v[0]; vv.y = v[1]; vv.z = v[2]; vv.w = v[3];
        reinterpret_cast<float4*>(big)[e * 32 + ch * 16 + tn] = vv;
      }
    }
  }
  float* sds = reinterpret_cast<float*>(&A_lds[0][0]);
  float* sdq = reinterpret_cast<float*>(&B_lds[0][0]);
#pragma unroll
  for (int ch = 0; ch < 2; ++ch)
#pragma unroll
    for (int b = 0; b < 4; ++b) {
      sds[tm * 128 + ch * 64 + tn * 4 + b] = sumf[ch][b];
      sdq[tm * 128 + ch * 64 + tn * 4 + b] = sqf[ch][b];
    }
  __syncthreads();
  if (tid < 128) {
    double s = 0.0, q = 0.0;
#pragma unroll
    for (int m2 = 0; m2 < 16; ++m2) {
      s += (double)sds[m2 * 128 + tid];
      q += (double)sdq[m2 * 128 + tid];
    }
    psum[(size_t)blockIdx.x * 128 + tid] = s;
    psq[(size_t)blockIdx.x * 128 + tid]  = q;
  }
}

// ---------------------------------------------------------------- final BN+ReLU+sum over K
__global__ __launch_bounds__(256)
void k_final(const float* __restrict__ big, const float* __restrict__ a3,
             const float* __restrict__ c3, float* __restrict__ out) {
  const int t = threadIdx.x;
  const int h = t & 127, ns = t >> 7;
  const size_t n = (size_t)blockIdx.x * 2 + ns;
  const float aa = a3[h], cc = c3[h];
  float s = 0.0f;
#pragma unroll
  for (int k = 0; k < KNN; ++k) {
    const float x = big[(n * KNN + k) * HDIM + h];
    s += fmaxf(fmaf(aa, x, cc), 0.0f);
  }
  out[n * HDIM + h] = s;
}

// ---------------------------------------------------------------- launch
extern "C" void kernel_launch(void* const* d_in, const int* in_sizes, int n_in,
                              void* d_out, int out_size, void* d_ws, size_t ws_size,
                              hipStream_t stream) {
  (void)in_sizes; (void)n_in; (void)out_size;
  const float* X   = (const float*)d_in[0];
  const float* W1  = (const float*)d_in[1];
  const float* b1  = (const float*)d_in[2];
  const float* g1  = (const float*)d_in[3];
  const float* be1 = (const float*)d_in[4];
  const float* W2  = (const float*)d_in[5];
  const float* b2  = (const float*)d_in[6];
  const float* g2  = (const float*)d_in[7];
  const float* be2 = (const float*)d_in[8];
  const float* W3  = (const float*)d_in[9];
  const float* b3  = (const float*)d_in[10];
  const float* g3  = (const float*)d_in[11];
  const float* be3 = (const float*)d_in[12];
  float* out = (float*)d_out;

  char* w = (char*)d_ws;
  size_t off = 0;
  auto carve = [&](size_t bytes) -> char* {
    char* p = w + off;
    off = (off + bytes + 255) & ~(size_t)255;
    return p;
  };
  float*  n2   = (float*)carve((size_t)N_PTS * 4);
  float*  P    = (float*)carve((size_t)N_PTS * HDIM * 4);
  float*  Q    = (float*)carve((size_t)N_PTS * HDIM * 4);
  int*    knn  = (int*)carve((size_t)NEDGE * 4);
  double* ps1  = (double*)carve((size_t)2048 * 128 * 8);
  double* pq1  = (double*)carve((size_t)2048 * 128 * 8);
  double* ps2  = (double*)carve((size_t)2048 * 128 * 8);
  double* pq2  = (double*)carve((size_t)2048 * 128 * 8);
  double* ps3  = (double*)carve((size_t)2048 * 128 * 8);
  double* pq3  = (double*)carve((size_t)2048 * 128 * 8);
  float*  a1   = (float*)carve(512);
  float*  c1   = (float*)carve(512);
  float*  a2   = (float*)carve(512);
  float*  c2   = (float*)carve(512);
  float*  a3   = (float*)carve(512);
  float*  c3   = (float*)carve(512);
  float*  big  = (float*)carve((size_t)NEDGE * HDIM * 4);
  if (off > ws_size) return;

  k_norms<<<dim3(N_PTS / 256), dim3(256), 0, stream>>>(X, n2);
  k_pq<<<dim3(N_PTS / 8), dim3(256), 0, stream>>>(X, W1, b1, P, Q);
  k_dist_topk<<<dim3(N_PTS / 32), dim3(256), 0, stream>>>(X, n2, knn);
  k_stats_edges<<<dim3(2048), dim3(256), 0, stream>>>(P, Q, knn, ps1, pq1);
  k_reduce_stats<<<dim3(128), dim3(256), 0, stream>>>(ps1, pq1, g1, be1, a1, c1);
  k_gemm<2><<<dim3(NEDGE / 128), dim3(256), 0, stream>>>(P, Q, knn, big, W2, b2, a1, c1, ps2, pq2);
  k_reduce_stats<<<dim3(128), dim3(256), 0, stream>>>(ps2, pq2, g2, be2, a2, c2);
  k_gemm<3><<<dim3(NEDGE / 128), dim3(256), 0, stream>>>(P, Q, knn, big, W3, b3, a2, c2, ps3, pq3);
  k_reduce_stats<<<dim3(128), dim3(256), 0, stream>>>(ps3, pq3, g3, be3, a3, c3);
  k_final<<<dim3(N_PTS / 2), dim3(256), 0, stream>>>(big, a3, c3, out);
}

// Round 8
// 1088.025 us; speedup vs baseline: 1.3702x; 1.1272x over previous
//
#include <hip/hip_runtime.h>

// EdgeConv block. Round 3 kernel, sixth submission (five GPU-acquisition timeouts; never run).
//  - k_split: one-time bf16 hi/lo decomposition of X (X = hi + lo + r, |r|<=2^-18|x|)
//  - k_dist_mfma: 32x32 j-tiles, dots via 3-split mfma_f32_32x32x16_bf16 (hi*hi+hi*lo+lo*hi),
//    operands global->VGPR (L2-resident, no LDS for dots). Swapped product C[j,i] so each
//    lane owns one i and 16 j-scores in acc regs. Approx filter (margin 1.0 >> 0.02 err bound)
//    gates a per-lane LDS ring; ballot-gated flush re-scores survivors with the EXACT r2 fp32
//    fmaf chain (identical ops + u64 tie keys) -> selection semantics == r2.
// Rest of pipeline unchanged from r2.

#define N_PTS 16384
#define FDIM  64
#define HDIM  128
#define KNN   16
#define NEDGE (N_PTS * KNN)

#define SENT_KEY 0xFF800000FFFFFFFFull
#define MAXU64   0xFFFFFFFFFFFFFFFFull
#define EPS_MARGIN 1.0f

typedef __attribute__((ext_vector_type(8)))  short bf16x8;
typedef __attribute__((ext_vector_type(16))) float f32x16;

// ---------------------------------------------------------------- norms
__global__ __launch_bounds__(256)
void k_norms(const float* __restrict__ X, float* __restrict__ n2) {
  const int r = blockIdx.x * 256 + threadIdx.x;
  const float4* x4 = reinterpret_cast<const float4*>(X) + (size_t)r * (FDIM / 4);
  float p[16];
#pragma unroll
  for (int i = 0; i < 16; ++i) {
    const float4 v = x4[i];
    p[i] = (v.x * v.x + v.y * v.y) + (v.z * v.z + v.w * v.w);
  }
#pragma unroll
  for (int s = 1; s < 16; s <<= 1) {
#pragma unroll
    for (int i = 0; i < 16; i += 2 * s) p[i] += p[i + s];
  }
  n2[r] = p[0];
}

// ---------------------------------------------------------------- bf16 hi/lo split of X
__global__ __launch_bounds__(256)
void k_split(const float* __restrict__ X, unsigned short* __restrict__ Xh,
             unsigned short* __restrict__ Xl) {
  const int t = blockIdx.x * 256 + threadIdx.x;           // 8 elems per thread
  const float4* X4 = reinterpret_cast<const float4*>(X);
  const float4 v0 = X4[(size_t)t * 2];
  const float4 v1 = X4[(size_t)t * 2 + 1];
  const float xs[8] = {v0.x, v0.y, v0.z, v0.w, v1.x, v1.y, v1.z, v1.w};
  unsigned int h[8], l[8];
#pragma unroll
  for (int e = 0; e < 8; ++e) {
    const unsigned int u = __float_as_uint(xs[e]);
    h[e] = (u + 0x7FFFu + ((u >> 16) & 1u)) >> 16;        // bf16 RNE
    const float hf = __uint_as_float(h[e] << 16);
    const float r = xs[e] - hf;                            // exact (Sterbenz)
    const unsigned int v = __float_as_uint(r);
    l[e] = (v + 0x7FFFu + ((v >> 16) & 1u)) >> 16;
  }
  uint4 hw, lw;
  hw.x = h[0] | (h[1] << 16); hw.y = h[2] | (h[3] << 16);
  hw.z = h[4] | (h[5] << 16); hw.w = h[6] | (h[7] << 16);
  lw.x = l[0] | (l[1] << 16); lw.y = l[2] | (l[3] << 16);
  lw.z = l[4] | (l[5] << 16); lw.w = l[6] | (l[7] << 16);
  reinterpret_cast<uint4*>(Xh)[t] = hw;
  reinterpret_cast<uint4*>(Xl)[t] = lw;
}

// ---------------------------------------------------------------- P,Q
__global__ __launch_bounds__(256)
void k_pq(const float* __restrict__ X, const float* __restrict__ W1,
          const float* __restrict__ b1, float* __restrict__ P, float* __restrict__ Q) {
  const int h4 = threadIdx.x & 31;
  const int rsub = threadIdx.x >> 5;
  const int row = blockIdx.x * 8 + rsub;
  const float* x = X + (size_t)row * FDIM;
  const float4* W14 = reinterpret_cast<const float4*>(W1);
  float4 at = make_float4(0.f, 0.f, 0.f, 0.f);
  float4 ab = make_float4(0.f, 0.f, 0.f, 0.f);
#pragma unroll 8
  for (int f = 0; f < FDIM; ++f) {
    const float xv = x[f];
    const float4 wt = W14[(size_t)f * 32 + h4];
    const float4 wb = W14[(size_t)(FDIM + f) * 32 + h4];
    at.x = fmaf(xv, wt.x, at.x); at.y = fmaf(xv, wt.y, at.y);
    at.z = fmaf(xv, wt.z, at.z); at.w = fmaf(xv, wt.w, at.w);
    ab.x = fmaf(xv, wb.x, ab.x); ab.y = fmaf(xv, wb.y, ab.y);
    ab.z = fmaf(xv, wb.z, ab.z); ab.w = fmaf(xv, wb.w, ab.w);
  }
  const float4 bb = reinterpret_cast<const float4*>(b1)[h4];
  float4 pv;
  pv.x = at.x - ab.x + bb.x; pv.y = at.y - ab.y + bb.y;
  pv.z = at.z - ab.z + bb.z; pv.w = at.w - ab.w + bb.w;
  reinterpret_cast<float4*>(P)[(size_t)row * 32 + h4] = pv;
  reinterpret_cast<float4*>(Q)[(size_t)row * 32 + h4] = ab;
}

// ---------------------------------------------------------------- MFMA distance + top-16
// Block: 256 thr = 4 waves, i-tile = 32 rows. Wave w handles j-tiles t (t%4==w), 128 each.
// Per tile: A = Xj (rows j), B = Xi^T (cols i); C[j,i] via 3-split bf16 MFMA.
// Lane owns i = i0+(lane&31); 16 j-scores in acc regs. thr = min over 8 owner slots
// of each slot's 16th-best (exact keys) -> approx filter (margin) -> ring -> exact flush.
// LDS: Xi fp32 [32][64] swizzled (c4 ^ (row&15)) @0 (8KB); thr [8][32] @8192 (1KB);
//      ring u32 [6][256] @9216 (6KB); merge mb u64 [32][8][16] aliases all (32KB).
__global__ __launch_bounds__(256, 2)
void k_dist_mfma(const float* __restrict__ X, const unsigned short* __restrict__ Xh,
                 const unsigned short* __restrict__ Xl, const float* __restrict__ n2g,
                 int* __restrict__ knn) {
  __shared__ __align__(16) char smem[32768];
  float* Xi = reinterpret_cast<float*>(smem);                    // [32][64] swizzled
  float* thr = reinterpret_cast<float*>(smem + 8192);            // [8][32]
  unsigned int* ring = reinterpret_cast<unsigned int*>(smem + 9216); // [6][256]

  const int tid = threadIdx.x;
  const int w = tid >> 6, lane = tid & 63;
  const int li = lane & 31, hf = lane >> 5;
  const int i0 = blockIdx.x * 32;
  const int slot = w * 2 + hf;

  const float4* X4 = reinterpret_cast<const float4*>(X);

  thr[tid] = __int_as_float(0x7f800000);
  // stage Xi fp32, swizzled for the exact-recompute reads
  for (int u = tid; u < 512; u += 256) {
    const int row = u >> 4, c4 = u & 15;
    const float4 v = X4[(size_t)(i0 + row) * 16 + c4];
    *reinterpret_cast<float4*>(&Xi[row * 64 + ((c4 ^ (row & 15)) * 4)]) = v;
  }

  // persistent B-frags (Xi hi/lo), lane supplies col li, k = s*16 + hf*8 + e
  bf16x8 bh[4], bl[4];
#pragma unroll
  for (int s = 0; s < 4; ++s) {
    const size_t o = (size_t)(i0 + li) * 64 + s * 16 + hf * 8;
    bh[s] = *reinterpret_cast<const bf16x8*>(Xh + o);
    bl[s] = *reinterpret_cast<const bf16x8*>(Xl + o);
  }
  const float n2i = n2g[i0 + li];

  unsigned long long list[16];
#pragma unroll
  for (int p = 0; p < 16; ++p) list[p] = SENT_KEY;
  int cnt = 0;
  float thrm = __int_as_float(0x7f800000);

  __syncthreads();

  auto flush = [&]() {
#pragma unroll 1
    for (int s = 0; s < 6; ++s) {
      if (s < cnt) {
        const unsigned int j = ring[s * 256 + tid];
        float a = 0.0f;
        const float4* xj4 = reinterpret_cast<const float4*>(X + (size_t)j * 64);
#pragma unroll
        for (int c4 = 0; c4 < 16; ++c4) {   // EXACT r2 fmaf chain, f ascending
          const float4 xiv =
              *reinterpret_cast<const float4*>(&Xi[li * 64 + ((c4 ^ (li & 15)) * 4)]);
          const float4 xjv = xj4[c4];
          a = fmaf(xiv.x, xjv.x, a); a = fmaf(xiv.y, xjv.y, a);
          a = fmaf(xiv.z, xjv.z, a); a = fmaf(xiv.w, xjv.w, a);
        }
        const float t = n2i + n2g[j];
        const float sd = __fsub_rn(t, __fmul_rn(2.0f, a));
        unsigned int ub = __float_as_uint(sd);
        ub = (ub & 0x80000000u) ? ~ub : (ub | 0x80000000u);
        const unsigned long long key = ((unsigned long long)ub << 32) | j;
        if (key < list[15]) {
#pragma unroll
          for (int q = 15; q >= 1; --q) {
            const unsigned long long prev = list[q - 1];
            unsigned long long cur = list[q];
            cur = (key < cur) ? key : cur;
            list[q] = (key < prev) ? prev : cur;
          }
          list[0] = (key < list[0]) ? key : list[0];
        }
      }
    }
    cnt = 0;
    const unsigned int ub16 = (unsigned int)(list[15] >> 32);
    const float tf = (ub16 & 0x80000000u) ? __uint_as_float(ub16 & 0x7fffffffu)
                                          : __uint_as_float(~ub16);
    thr[slot * 32 + li] = tf;
    thrm = fminf(thrm, tf);
  };

  for (int ct = 0; ct < 128; ++ct) {
    const int jb = (ct * 4 + w) * 32;
    if ((ct & 3) == 0) {  // refresh shared threshold (stale = larger = safe)
      float m = thr[li];
#pragma unroll
      for (int q = 1; q < 8; ++q) m = fminf(m, thr[q * 32 + li]);
      thrm = m;
    }
    bf16x8 ah[4], al[4];
#pragma unroll
    for (int s = 0; s < 4; ++s) {
      const size_t o = (size_t)(jb + li) * 64 + s * 16 + hf * 8;
      ah[s] = *reinterpret_cast<const bf16x8*>(Xh + o);
      al[s] = *reinterpret_cast<const bf16x8*>(Xl + o);
    }
    float4 nj[4];
#pragma unroll
    for (int q = 0; q < 4; ++q)
      nj[q] = *reinterpret_cast<const float4*>(n2g + jb + q * 8 + hf * 4);

    f32x16 acc0 = {0,0,0,0,0,0,0,0,0,0,0,0,0,0,0,0};
    f32x16 acc1 = {0,0,0,0,0,0,0,0,0,0,0,0,0,0,0,0};
#pragma unroll
    for (int s = 0; s < 4; ++s) {
      acc0 = __builtin_amdgcn_mfma_f32_32x32x16_bf16(ah[s], bh[s], acc0, 0, 0, 0);
      acc1 = __builtin_amdgcn_mfma_f32_32x32x16_bf16(ah[s], bl[s], acc1, 0, 0, 0);
      acc1 = __builtin_amdgcn_mfma_f32_32x32x16_bf16(al[s], bh[s], acc1, 0, 0, 0);
    }

    const float lim = thrm + EPS_MARGIN;
#pragma unroll
    for (int r = 0; r < 16; ++r) {
      const float dot = acc0[r] + acc1[r];
      const float njv = (r & 2) ? ((r & 1) ? nj[r >> 2].w : nj[r >> 2].z)
                                : ((r & 1) ? nj[r >> 2].y : nj[r >> 2].x);
      const float sv = fmaf(-2.0f, dot, n2i + njv);
      if (sv <= lim) {
        ring[cnt * 256 + tid] = (unsigned int)(jb + (r & 3) + 8 * (r >> 2) + 4 * hf);
        ++cnt;
      }
      if ((r & 1) && __any(cnt >= 5)) flush();
    }
  }
  flush();  // drain

  // merge: 8 sorted 16-lists per i -> top 16
  __syncthreads();
  unsigned long long* mb = reinterpret_cast<unsigned long long*>(smem);  // 32KB alias
#pragma unroll
  for (int p = 0; p < 16; ++p) mb[((size_t)li * 8 + slot) * 16 + p] = list[p];
  __syncthreads();
  if (tid < 32) {
    int pp[8] = {0, 0, 0, 0, 0, 0, 0, 0};
    for (int pick = 0; pick < KNN; ++pick) {
      unsigned long long best = MAXU64; int bq = 0;
#pragma unroll
      for (int q = 0; q < 8; ++q) {
        const unsigned long long cand =
            (pp[q] < 16) ? mb[((size_t)tid * 8 + q) * 16 + pp[q]] : MAXU64;
        if (cand < best) { best = cand; bq = q; }
      }
      pp[bq]++;
      knn[(size_t)(i0 + tid) * KNN + pick] = (int)(unsigned int)(best & 0xFFFFFFFFULL);
    }
  }
}

// ---------------------------------------------------------------- stats of pre1
__global__ __launch_bounds__(256)
void k_stats_edges(const float* __restrict__ P, const float* __restrict__ Q,
                   const int* __restrict__ idx,
                   double* __restrict__ psum, double* __restrict__ psq) {
  __shared__ double sd[2][128];
  __shared__ double qd[2][128];
  const int t = threadIdx.x;
  const int h = t & 127, half = t >> 7;
  const size_t e0 = (size_t)blockIdx.x * 128;
  double s = 0.0, q = 0.0;
  for (int it = 0; it < 64; ++it) {
    const size_t e = e0 + (size_t)it * 2 + half;
    const int n = (int)(e >> 4);
    const int j = idx[e];
    const float v = P[(size_t)n * HDIM + h] + Q[(size_t)j * HDIM + h];
    s += (double)v;
    q += (double)v * (double)v;
  }
  sd[half][h] = s; qd[half][h] = q;
  __syncthreads();
  if (t < 128) {
    psum[(size_t)blockIdx.x * 128 + t] = sd[0][t] + sd[1][t];
    psq[(size_t)blockIdx.x * 128 + t]  = qd[0][t] + qd[1][t];
  }
}

// ---------------------------------------------------------------- stats reduce -> a,c
__global__ __launch_bounds__(256)
void k_reduce_stats(const double* __restrict__ psum, const double* __restrict__ psq,
                    const float* __restrict__ g, const float* __restrict__ beta,
                    float* __restrict__ aout, float* __restrict__ cout) {
  __shared__ double sbuf[256];
  __shared__ double qbuf[256];
  const int h = blockIdx.x, t = threadIdx.x;
  double s = 0.0, q = 0.0;
  for (int i = t; i < 2048; i += 256) {
    s += psum[(size_t)i * 128 + h];
    q += psq[(size_t)i * 128 + h];
  }
  sbuf[t] = s; qbuf[t] = q;
  __syncthreads();
  for (int st = 128; st > 0; st >>= 1) {
    if (t < st) { sbuf[t] += sbuf[t + st]; qbuf[t] += qbuf[t + st]; }
    __syncthreads();
  }
  if (t == 0) {
    const double cntd = (double)NEDGE;
    const double mu = sbuf[0] / cntd;
    double var = qbuf[0] / cntd - mu * mu;
    if (var < 0.0) var = 0.0;
    const double rs = 1.0 / sqrt(var + 1e-5);
    const double a = (double)g[h] * rs;
    aout[h] = (float)a;
    cout[h] = (float)((double)beta[h] - mu * a);
  }
}

// ---------------------------------------------------------------- GEMM (layers 2 & 3)
template <int MODE>
__global__ __launch_bounds__(256, 2)
void k_gemm(const float* __restrict__ P, const float* __restrict__ Q,
            const int* __restrict__ idx, float* __restrict__ big,
            const float* __restrict__ Wg, const float* __restrict__ bias,
            const float* __restrict__ aff_a, const float* __restrict__ aff_c,
            double* __restrict__ psum, double* __restrict__ psq) {
  __shared__ float A_lds[32][132];
  __shared__ float B_lds[32][132];
  const int tid = threadIdx.x;
  const int tm = tid & 15, tn = tid >> 4;
  const size_t e0 = (size_t)blockIdx.x * 128;

  float acc[2][2][4][4] = {};

  for (int kk = 0; kk < 128; kk += 32) {
    __syncthreads();
    {
      const int k4 = tid & 7;
      const int mrow = tid >> 3;
      const float4 av = reinterpret_cast<const float4*>(aff_a)[(kk >> 2) + k4];
      const float4 cv = reinterpret_cast<const float4*>(aff_c)[(kk >> 2) + k4];
#pragma unroll
      for (int p = 0; p < 4; ++p) {
        const int m = p * 32 + mrow;
        const size_t e = e0 + m;
        float4 hv;
        if (MODE == 2) {
          const int n = (int)(e >> 4);
          const int j = idx[e];
          const float4 pv = reinterpret_cast<const float4*>(P)[(size_t)n * 32 + (kk >> 2) + k4];
          const float4 qv = reinterpret_cast<const float4*>(Q)[(size_t)j * 32 + (kk >> 2) + k4];
          hv.x = pv.x + qv.x; hv.y = pv.y + qv.y; hv.z = pv.z + qv.z; hv.w = pv.w + qv.w;
        } else {
          hv = reinterpret_cast<const float4*>(big)[e * 32 + (kk >> 2) + k4];
        }
        A_lds[k4 * 4 + 0][m] = fmaxf(fmaf(av.x, hv.x, cv.x), 0.0f);
        A_lds[k4 * 4 + 1][m] = fmaxf(fmaf(av.y, hv.y, cv.y), 0.0f);
        A_lds[k4 * 4 + 2][m] = fmaxf(fmaf(av.z, hv.z, cv.z), 0.0f);
        A_lds[k4 * 4 + 3][m] = fmaxf(fmaf(av.w, hv.w, cv.w), 0.0f);
      }
    }
    {
      const int f4c = tid & 31;
      const int rb = tid >> 5;
#pragma unroll
      for (int p = 0; p < 4; ++p) {
        const int r = p * 8 + rb;
        const float4 wv = reinterpret_cast<const float4*>(Wg)[(size_t)(kk + r) * 32 + f4c];
        *reinterpret_cast<float4*>(&B_lds[r][f4c * 4]) = wv;
      }
    }
    __syncthreads();
#pragma unroll 4
    for (int k = 0; k < 32; ++k) {
      const float4 a0 = *reinterpret_cast<const float4*>(&A_lds[k][tm * 4]);
      const float4 a1 = *reinterpret_cast<const float4*>(&A_lds[k][64 + tm * 4]);
      const float4 b0 = *reinterpret_cast<const float4*>(&B_lds[k][tn * 4]);
      const float4 b1 = *reinterpret_cast<const float4*>(&B_lds[k][64 + tn * 4]);
      const float avv[2][4] = {{a0.x, a0.y, a0.z, a0.w}, {a1.x, a1.y, a1.z, a1.w}};
      const float bvv[2][4] = {{b0.x, b0.y, b0.z, b0.w}, {b1.x, b1.y, b1.z, b1.w}};
#pragma unroll
      for (int rh = 0; rh < 2; ++rh)
#pragma unroll
        for (int a = 0; a < 4; ++a)
#pragma unroll
          for (int ch = 0; ch < 2; ++ch)
#pragma unroll
            for (int b = 0; b < 4; ++b)
              acc[rh][ch][a][b] = fmaf(avv[rh][a], bvv[ch][b], acc[rh][ch][a][b]);
    }
  }

  __syncthreads();
  float sumf[2][4] = {{0, 0, 0, 0}, {0, 0, 0, 0}};
  float sqf[2][4]  = {{0, 0, 0, 0}, {0, 0, 0, 0}};
  const float4 bbl = reinterpret_cast<const float4*>(bias)[tn];
  const float4 bbh = reinterpret_cast<const float4*>(bias)[16 + tn];
  const float bb[2][4] = {{bbl.x, bbl.y, bbl.z, bbl.w}, {bbh.x, bbh.y, bbh.z, bbh.w}};
#pragma unroll
  for (int rh = 0; rh < 2; ++rh) {
#pragma unroll
    for (int a = 0; a < 4; ++a) {
      const size_t e = e0 + rh * 64 + tm * 4 + a;
#pragma unroll
      for (int ch = 0; ch < 2; ++ch) {
        float v[4];
#pragma unroll
        for (int b = 0; b < 4; ++b) {
          v[b] = acc[rh][ch][a][b] + bb[ch][b];
          sumf[ch][b] += v[b];
          sqf[ch][b] = fmaf(v[b], v[b], sqf[ch][b]);
        }
        float4 vv; vv.x = v[0]; vv.y = v[1]; vv.z = v[2]; vv.w = v[3];
        reinterpret_cast<float4*>(big)[e * 32 + ch * 16 + tn] = vv;
      }
    }
  }
  float* sds = reinterpret_cast<float*>(&A_lds[0][0]);
  float* sdq = reinterpret_cast<float*>(&B_lds[0][0]);
#pragma unroll
  for (int ch = 0; ch < 2; ++ch)
#pragma unroll
    for (int b = 0; b < 4; ++b) {
      sds[tm * 128 + ch * 64 + tn * 4 + b] = sumf[ch][b];
      sdq[tm * 128 + ch * 64 + tn * 4 + b] = sqf[ch][b];
    }
  __syncthreads();
  if (tid < 128) {
    double s = 0.0, q = 0.0;
#pragma unroll
    for (int m2 = 0; m2 < 16; ++m2) {
      s += (double)sds[m2 * 128 + tid];
      q += (double)sdq[m2 * 128 + tid];
    }
    psum[(size_t)blockIdx.x * 128 + tid] = s;
    psq[(size_t)blockIdx.x * 128 + tid]  = q;
  }
}

// ---------------------------------------------------------------- final BN+ReLU+sum over K
__global__ __launch_bounds__(256)
void k_final(const float* __restrict__ big, const float* __restrict__ a3,
             const float* __restrict__ c3, float* __restrict__ out) {
  const int t = threadIdx.x;
  const int h = t & 127, ns = t >> 7;
  const size_t n = (size_t)blockIdx.x * 2 + ns;
  const float aa = a3[h], cc = c3[h];
  float s = 0.0f;
#pragma unroll
  for (int k = 0; k < KNN; ++k) {
    const float x = big[(n * KNN + k) * HDIM + h];
    s += fmaxf(fmaf(aa, x, cc), 0.0f);
  }
  out[n * HDIM + h] = s;
}

// ---------------------------------------------------------------- launch
extern "C" void kernel_launch(void* const* d_in, const int* in_sizes, int n_in,
                              void* d_out, int out_size, void* d_ws, size_t ws_size,
                              hipStream_t stream) {
  (void)in_sizes; (void)n_in; (void)out_size;
  const float* X   = (const float*)d_in[0];
  const float* W1  = (const float*)d_in[1];
  const float* b1  = (const float*)d_in[2];
  const float* g1  = (const float*)d_in[3];
  const float* be1 = (const float*)d_in[4];
  const float* W2  = (const float*)d_in[5];
  const float* b2  = (const float*)d_in[6];
  const float* g2  = (const float*)d_in[7];
  const float* be2 = (const float*)d_in[8];
  const float* W3  = (const float*)d_in[9];
  const float* b3  = (const float*)d_in[10];
  const float* g3  = (const float*)d_in[11];
  const float* be3 = (const float*)d_in[12];
  float* out = (float*)d_out;

  char* w = (char*)d_ws;
  size_t off = 0;
  auto carve = [&](size_t bytes) -> char* {
    char* p = w + off;
    off = (off + bytes + 255) & ~(size_t)255;
    return p;
  };
  float*  n2   = (float*)carve((size_t)N_PTS * 4);
  unsigned short* Xh = (unsigned short*)carve((size_t)N_PTS * FDIM * 2);
  unsigned short* Xl = (unsigned short*)carve((size_t)N_PTS * FDIM * 2);
  float*  P    = (float*)carve((size_t)N_PTS * HDIM * 4);
  float*  Q    = (float*)carve((size_t)N_PTS * HDIM * 4);
  int*    knn  = (int*)carve((size_t)NEDGE * 4);
  double* ps1  = (double*)carve((size_t)2048 * 128 * 8);
  double* pq1  = (double*)carve((size_t)2048 * 128 * 8);
  double* ps2  = (double*)carve((size_t)2048 * 128 * 8);
  double* pq2  = (double*)carve((size_t)2048 * 128 * 8);
  double* ps3  = (double*)carve((size_t)2048 * 128 * 8);
  double* pq3  = (double*)carve((size_t)2048 * 128 * 8);
  float*  a1   = (float*)carve(512);
  float*  c1   = (float*)carve(512);
  float*  a2   = (float*)carve(512);
  float*  c2   = (float*)carve(512);
  float*  a3   = (float*)carve(512);
  float*  c3   = (float*)carve(512);
  float*  big  = (float*)carve((size_t)NEDGE * HDIM * 4);
  if (off > ws_size) return;

  k_norms<<<dim3(N_PTS / 256), dim3(256), 0, stream>>>(X, n2);
  k_split<<<dim3(512), dim3(256), 0, stream>>>(X, Xh, Xl);
  k_pq<<<dim3(N_PTS / 8), dim3(256), 0, stream>>>(X, W1, b1, P, Q);
  k_dist_mfma<<<dim3(N_PTS / 32), dim3(256), 0, stream>>>(X, Xh, Xl, n2, knn);
  k_stats_edges<<<dim3(2048), dim3(256), 0, stream>>>(P, Q, knn, ps1, pq1);
  k_reduce_stats<<<dim3(128), dim3(256), 0, stream>>>(ps1, pq1, g1, be1, a1, c1);
  k_gemm<2><<<dim3(NEDGE / 128), dim3(256), 0, stream>>>(P, Q, knn, big, W2, b2, a1, c1, ps2, pq2);
  k_reduce_stats<<<dim3(128), dim3(256), 0, stream>>>(ps2, pq2, g2, be2, a2, c2);
  k_gemm<3><<<dim3(NEDGE / 128), dim3(256), 0, stream>>>(P, Q, knn, big, W3, b3, a2, c2, ps3, pq3);
  k_reduce_stats<<<dim3(128), dim3(256), 0, stream>>>(ps3, pq3, g3, be3, a3, c3);
  k_final<<<dim3(N_PTS / 2), dim3(256), 0, stream>>>(big, a3, c3, out);
}